// Round 9
// baseline (384.881 us; speedup 1.0000x reference)
//
#include <hip/hip_runtime.h>

// CrossModalAttentionScorer — round 17: r16 with the A-read swizzle FIXED.
// B=16, R=1024, T=512, D=H=1024.
//
// r16 bug: fp32-A ds_read used rA*64 + g*16; staging stores slot s of row r
// at global col-group s ^ ((r>>1)&3), so the read must use slot
// g ^ ((fr>>1)&3) (= fs2). bp/bq had it right; af didn't. Fixed here.
//
//   K1 prep_all: M2 = NT(Wr,Wq); Ws16; wqbr(+16); query16 + h1. (2562 blks)
//   K2 qp:       Qp = NT(query16, M2), r13's counted-vmcnt 4-slot (best).
//   K3 fused:    accS = NT(region_f32, Qp)+cvec, accH = NT(region, Ws2.q),
//                h1 in epilogue. A staged fp32 (2 gl16/lane), cvt8 after
//                ds_read (identical rounding to old K1 conversion). nt==0
//                blocks also emit rdvec = region.Ws0 from the fp32 tiles.
//   K4 combine:  4 chunk-stats per row (r13).
//
// Hard-won constraints (measured):
//   - counted-vmcnt on K3's 128^2 tile: null-to-negative (r10/r11).
//   - per-block __threadfence fan-in: +100us fence storm (r12). Never.
//   - conv/GEMM same-launch overlap: additive, no hiding (r14).
//   - K2 BK=64: null-to-slightly-negative (r15). Reverted.
//   - fixed overhead ~95-100us, launch-count-independent (r12/r13).
//   - LDS staging permutation NEVER cancels on read: reader must XOR (r16).

#define BD 16
#define RD 1024
#define TD 512
#define DD 1024
#define BR (BD * RD)

typedef _Float16 half8 __attribute__((ext_vector_type(8)));
typedef _Float16 half4 __attribute__((ext_vector_type(4)));
typedef float floatx4 __attribute__((ext_vector_type(4)));

__device__ __forceinline__ float wave_sum(float v) {
#pragma unroll
  for (int off = 32; off > 0; off >>= 1) v += __shfl_down(v, off);
  return v;
}

__device__ __forceinline__ half8 cvt8(float4 a, float4 b) {
  half8 h = {(_Float16)a.x, (_Float16)a.y, (_Float16)a.z, (_Float16)a.w,
             (_Float16)b.x, (_Float16)b.y, (_Float16)b.z, (_Float16)b.w};
  return h;
}

// Async global->LDS, 16 B/lane. LDS dest is wave-uniform base + lane*16.
__device__ __forceinline__ void gl16(const _Float16* g, _Float16* l) {
  __builtin_amdgcn_global_load_lds(
      (const __attribute__((address_space(1))) void*)g,
      (__attribute__((address_space(3))) void*)l, 16, 0, 0);
}
__device__ __forceinline__ void gl16b(const void* g, void* l) {
  __builtin_amdgcn_global_load_lds(
      (const __attribute__((address_space(1))) void*)g,
      (__attribute__((address_space(3))) void*)l, 16, 0, 0);
}

#define VMW_(N) asm volatile("s_waitcnt vmcnt(" #N ")" ::: "memory")
#define VMW(N) VMW_(N)
#define BARR                        \
  __builtin_amdgcn_s_barrier();     \
  asm volatile("" ::: "memory")

// ---------------- K1: only what K2 (and K3's small vectors) need.
// blk [0,256):      M2 = NT(Wr,Wq) 64x64 tile
// blk [256,258):    Ws1|Ws2 -> fp16
// blk [258,514):    wqbr = Wq @ br
// blk [514,2562):   query -> fp16, h1 = query.Ws1 (4 rows/block)
__global__ __launch_bounds__(256) void prep_all(
    const float* __restrict__ Wr, const float* __restrict__ Wq,
    const float* __restrict__ Ws, const float* __restrict__ br,
    const float* __restrict__ query,
    _Float16* __restrict__ M2, _Float16* __restrict__ Ws16,
    float* __restrict__ wqbr, _Float16* __restrict__ wqbr16,
    _Float16* __restrict__ q16, float* __restrict__ h1) {
  __shared__ __align__(16) _Float16 lds[2 * 2 * 2048];  // 16 KB (M2 path)
  const int blk = blockIdx.x, tid = threadIdx.x;

  if (blk < 256) {  // ---- M2 = NT(Wr, Wq), 64x64 tile, K=1024
    const int m0 = (blk >> 4) * 64, n0 = (blk & 15) * 64;
    const int lane = tid & 63, w = tid >> 6;
    const int wr = w >> 1, wc = w & 1;
    const int srow = tid >> 2, slot = tid & 3;
    const int scol = (slot ^ ((srow >> 1) & 3)) * 8;
    const long offA = (long)(m0 + srow) * DD + scol;
    const long offB = (long)(n0 + srow) * DD + scol;
    const int wofs = srow * 32 + slot * 8;
    const int NK = DD / 32;
    float4 a0, a1, b0, b1;
    a0 = *(const float4*)(Wr + offA); a1 = *(const float4*)(Wr + offA + 4);
    b0 = *(const float4*)(Wq + offB); b1 = *(const float4*)(Wq + offB + 4);
    *(int4*)&lds[wofs] = *(int4*)&(const half8&)cvt8(a0, a1);
    {
      half8 hb = cvt8(b0, b1);
      *(half8*)&lds[2048 + wofs] = hb;
    }
    a0 = *(const float4*)(Wr + offA + 32); a1 = *(const float4*)(Wr + offA + 36);
    b0 = *(const float4*)(Wq + offB + 32); b1 = *(const float4*)(Wq + offB + 36);
    __syncthreads();
    floatx4 acc[2][2] = {};
    const int fr = lane & 15, g = lane >> 4;
    const int fs = (g ^ ((fr >> 1) & 3)) * 8;
    for (int kt = 0; kt < NK; ++kt) {
      const int cur = (kt & 1) * 4096, nxt = ((kt + 1) & 1) * 4096;
      if (kt + 1 < NK) {
        half8 ha = cvt8(a0, a1), hb = cvt8(b0, b1);
        *(half8*)&lds[nxt + wofs] = ha;
        *(half8*)&lds[nxt + 2048 + wofs] = hb;
      }
      if (kt + 2 < NK) {
        const long go = (long)(kt + 2) * 32;
        a0 = *(const float4*)(Wr + offA + go); a1 = *(const float4*)(Wr + offA + go + 4);
        b0 = *(const float4*)(Wq + offB + go); b1 = *(const float4*)(Wq + offB + go + 4);
      }
      half8 af[2], bf[2];
#pragma unroll
      for (int i = 0; i < 2; ++i)
        af[i] = *(const half8*)&lds[cur + (32 * wr + 16 * i + fr) * 32 + fs];
#pragma unroll
      for (int j = 0; j < 2; ++j)
        bf[j] = *(const half8*)&lds[cur + 2048 + (32 * wc + 16 * j + fr) * 32 + fs];
#pragma unroll
      for (int i = 0; i < 2; ++i)
#pragma unroll
        for (int j = 0; j < 2; ++j)
          acc[i][j] = __builtin_amdgcn_mfma_f32_16x16x32_f16(af[i], bf[j], acc[i][j], 0, 0, 0);
      __syncthreads();
    }
    const int cr = g * 4, cc = fr;
#pragma unroll
    for (int i = 0; i < 2; ++i)
#pragma unroll
      for (int r = 0; r < 4; ++r)
#pragma unroll
        for (int j = 0; j < 2; ++j)
          M2[(long)(m0 + 32 * wr + 16 * i + cr + r) * DD + n0 + 32 * wc + 16 * j + cc] =
              (_Float16)acc[i][j][r];
  } else if (blk < 258) {  // ---- Ws1|Ws2
    const long i = (long)(blk - 256) * 1024 + tid * 4;
    const float4 v = *(const float4*)&Ws[DD + i];
    half4 h = {(_Float16)v.x, (_Float16)v.y, (_Float16)v.z, (_Float16)v.w};
    *(half4*)&Ws16[i] = h;
  } else if (blk < 514) {  // ---- wqbr = Wq @ br
    const int row = (blk - 258) * 4 + (tid >> 6);
    const int lane = tid & 63;
    const float* x = Wq + (long)row * DD;
    float s = 0.f;
    for (int k = lane; k < DD; k += 64) s += x[k] * br[k];
    s = wave_sum(s);
    if (lane == 0) {
      wqbr[row] = s;
      wqbr16[row] = (_Float16)s;
    }
  } else {  // ---- query conv + h1 = q.Ws1, wave-per-row
    const int wid = tid >> 6, lane = tid & 63;
    const long row = (long)(blk - 514) * 4 + wid;
    const float* src = query + row * DD;
    _Float16* dst = q16 + row * DD;
    float hq = 0.f;
#pragma unroll
    for (int it = 0; it < 4; ++it) {
      const int c = it * 256 + lane * 4;
      const float4 v = *(const float4*)&src[c];
      const float4 w1 = *(const float4*)&Ws[DD + c];
      half4 h = {(_Float16)v.x, (_Float16)v.y, (_Float16)v.z, (_Float16)v.w};
      *(half4*)&dst[c] = h;
      hq += v.x * w1.x + v.y * w1.y + v.z * w1.z + v.w * w1.w;
    }
    hq = wave_sum(hq);
    if (lane == 0) h1[row] = hq;
  }
}

// ---------------- K2: Qp = NT(query16, M2) — r13 counted-vmcnt 4-slot.
#define STAGE2(hh, sl)                                  \
  {                                                     \
    const long go_ = (long)(hh) * 32;                   \
    gl16(gA + go_, &lds[(sl) * 8192 + wbase]);          \
    gl16(gB + go_, &lds[(sl) * 8192 + 4096 + wbase]);   \
  }

#define COMP2(h, sl)                                                           \
  {                                                                            \
    half8 af[2], bf[4];                                                        \
    _Pragma("unroll") for (int i = 0; i < 2; ++i)                              \
      af[i] = *(const half8*)&lds[(sl) * 8192 + (32 * wr + 16 * i + fr) * 32 + fs]; \
    _Pragma("unroll") for (int j = 0; j < 4; ++j)                              \
      bf[j] = *(const half8*)&lds[(sl) * 8192 + 4096 + (64 * wc + 16 * j + fr) * 32 + fs]; \
    if (wc == 0) {                                                             \
      const half8 wb = *(const half8*)&wq_lds[(h) * 32 + g * 8];               \
      _Pragma("unroll") for (int i = 0; i < 2; ++i)                            \
        _Pragma("unroll") for (int e = 0; e < 8; ++e)                          \
          cvp[i] += (float)af[i][e] * (float)wb[e];                            \
    }                                                                          \
    __builtin_amdgcn_s_setprio(1);                                             \
    _Pragma("unroll") for (int i = 0; i < 2; ++i)                              \
      _Pragma("unroll") for (int j = 0; j < 4; ++j)                            \
        acc[i][j] = __builtin_amdgcn_mfma_f32_16x16x32_f16(af[i], bf[j], acc[i][j], 0, 0, 0); \
    __builtin_amdgcn_s_setprio(0);                                             \
  }

__global__ __launch_bounds__(512, 4) void qp_gemm(
    const _Float16* __restrict__ A, const _Float16* __restrict__ B,
    _Float16* __restrict__ C, const _Float16* __restrict__ wq16,
    float* __restrict__ cvec) {
  __shared__ __align__(16) _Float16 lds[4 * 8192];   // 64 KB: 4 slots
  __shared__ __align__(16) _Float16 wq_lds[1024];
  const int lin = blockIdx.x;
  const int s = lin & 7, u = lin >> 3;  // XCD s owns m-strip [8s, 8s+8)
  const int mt = s * 8 + (u >> 3), nt = u & 7;
  const int m0 = mt * 128, n0 = nt * 128;
  const int tid = threadIdx.x, lane = tid & 63, w = tid >> 6;
  const int wr = w >> 1, wc = w & 1;

  const int lrow = lane >> 2, slot = lane & 3;
  const int scol = (slot ^ ((lrow >> 1) & 3)) * 8;
  const int srow = 16 * w + lrow;  // 0..127
  const _Float16* gA = A + (long)(m0 + srow) * DD + scol;
  const _Float16* gB = B + (long)(n0 + srow) * DD + scol;
  const int wbase = 512 * w;  // halfs: lane l lands at wbase + 8*l

  if (tid < 128) *(int4*)&wq_lds[tid * 8] = *(const int4*)&wq16[tid * 8];
  __syncthreads();  // wq_lds visible; clean vmcnt slate

  floatx4 acc[2][4] = {};
  float cvp[2] = {0.f, 0.f};
  const int fr = lane & 15, g = lane >> 4;
  const int fs = (g ^ ((fr >> 1) & 3)) * 8;

  STAGE2(0, 0); STAGE2(1, 1); STAGE2(2, 2);  // 6 outstanding
  VMW(4); BARR;                              // slot 0 landed everywhere

  for (int hb = 0; hb < 28; hb += 4) {
    STAGE2(hb + 3, 3); COMP2(hb + 0, 0); VMW(4); BARR;
    STAGE2(hb + 4, 0); COMP2(hb + 1, 1); VMW(4); BARR;
    STAGE2(hb + 5, 1); COMP2(hb + 2, 2); VMW(4); BARR;
    STAGE2(hb + 6, 2); COMP2(hb + 3, 3); VMW(4); BARR;
  }
  STAGE2(31, 3); COMP2(28, 0); VMW(4); BARR;
  COMP2(29, 1); VMW(2); BARR;
  COMP2(30, 2); VMW(0); BARR;
  COMP2(31, 3);

  if (wc == 0 && nt == 0) {
#pragma unroll
    for (int i = 0; i < 2; ++i) {
      float c = cvp[i];
      c += __shfl_xor(c, 16);
      c += __shfl_xor(c, 32);
      if (lane < 16) cvec[m0 + 32 * wr + 16 * i + lane] = c;
    }
  }

  const int cr = g * 4, cc = fr;
#pragma unroll
  for (int i = 0; i < 2; ++i)
#pragma unroll
    for (int r = 0; r < 4; ++r)
#pragma unroll
      for (int j = 0; j < 4; ++j)
        C[(long)(m0 + 32 * wr + 16 * i + cr + r) * DD + n0 + 64 * wc + 16 * j + cc] =
            (_Float16)acc[i][j][r];
}

// ---------------- K3: fused S/H GEMM + split-softmax stats, A = fp32 direct.
// 8 waves 2(m) x 4(n); wave 64x32. LDS slot (32 KB): A32-c0 [0,8K),
// A32-c1 [8K,16K), P [16K,24K), Q [24K,32K). 2 slots = 64 KB. nt==0 blocks
// also accumulate rdvec = region.Ws0 from the fp32 tiles.
__global__ __launch_bounds__(512, 4) void gemm_fused(
    const float* __restrict__ Af, const _Float16* __restrict__ B0,
    const _Float16* __restrict__ B1,
    float* __restrict__ Ms, float* __restrict__ Ls, float* __restrict__ Hs,
    const float* __restrict__ cvec, const float* __restrict__ h1,
    const _Float16* __restrict__ wsh, const float* __restrict__ ws0,
    float* __restrict__ rdvec, long sA, long sB) {
  __shared__ __align__(16) char ldsb[2 * 32768];  // 64 KB
  __shared__ __align__(16) _Float16 wlds[1024];   // Ws2 fp16
  __shared__ __align__(16) float ws0l[1024];      // Ws0 fp32

  const int lin = blockIdx.x;
  const int s = lin & 7, u = lin >> 3;  // XCD s owns batches 2s, 2s+1
  const int b = 2 * s + (u >> 5);
  const int t = u & 31;
  const int mt = t >> 2, nt = t & 3;
  const int m0 = mt * 128, n0 = nt * 128;
  const float* Ab = Af + (long)b * sA;
  B0 += (long)b * sB;
  B1 += (long)b * sB;

  const int tid = threadIdx.x, lane = tid & 63, w = tid >> 6;
  const int wr = w >> 2, wc = w & 3;  // 2 x 4

  const int lrow = lane >> 2, slot = lane & 3;
  const int scol = (slot ^ ((lrow >> 1) & 3)) * 8;
  const int srow = 16 * w + lrow;  // 0..127
  const float*    gA = Ab + (long)(m0 + srow) * DD + scol;
  const _Float16* gP = B0 + (long)(n0 + srow) * DD + scol;
  const _Float16* gQ = B1 + (long)(n0 + srow) * DD + scol;
  const int wB = 1024 * w;

  if (tid < 128) *(int4*)&wlds[tid * 8] = *(const int4*)&wsh[1024 + tid * 8];
  if (tid >= 256) *(float4*)&ws0l[(tid - 256) * 4] = *(const float4*)&ws0[(tid - 256) * 4];

  gl16b(gA,     ldsb + wB);
  gl16b(gA + 4, ldsb + 8192 + wB);
  gl16b(gP,     ldsb + 16384 + wB);
  gl16b(gQ,     ldsb + 24576 + wB);
  __syncthreads();

  floatx4 accS[4][2] = {};
  floatx4 accH[4][2] = {};
  float rdp = 0.f;
  const int fr = lane & 15, g = lane >> 4;
  const int fs2 = (g ^ ((fr >> 1) & 3)) * 16;  // byte slot offset (READ XOR)
  const bool doRd = (nt == 0);
  const int rr = tid >> 2, c4 = tid & 3;       // rdvec: 4 threads per row
  const int sR = c4 ^ ((rr >> 1) & 3);
  const int NK = DD / 32;

  for (int kt = 0; kt < NK; ++kt) {
    const int cur = (kt & 1) * 32768;
    const int nxt = cur ^ 32768;
    if (kt + 1 < NK) {
      const long go = (long)(kt + 1) * 32;
      gl16b(gA + go,     ldsb + nxt + wB);
      gl16b(gA + go + 4, ldsb + nxt + 8192 + wB);
      gl16b(gP + go,     ldsb + nxt + 16384 + wB);
      gl16b(gQ + go,     ldsb + nxt + 24576 + wB);
    }
    half8 af[4], bp[2], bq[2];
#pragma unroll
    for (int i = 0; i < 4; ++i) {
      const int rA = 64 * wr + 16 * i + fr;
      const float4 lo = *(const float4*)&ldsb[cur + rA * 64 + fs2];
      const float4 hi = *(const float4*)&ldsb[cur + 8192 + rA * 64 + fs2];
      af[i] = cvt8(lo, hi);  // identical rounding to the old K1 conversion
    }
#pragma unroll
    for (int j = 0; j < 2; ++j)
      bp[j] = *(const half8*)&ldsb[cur + 16384 + (32 * wc + 16 * j + fr) * 64 + fs2];
#pragma unroll
    for (int j = 0; j < 2; ++j)
      bq[j] = *(const half8*)&ldsb[cur + 24576 + (32 * wc + 16 * j + fr) * 64 + fs2];
    if (doRd) {  // rdvec partial: row rr, float-cols kt*32 + 8*c4 .. +8
      const float4 alo = *(const float4*)&ldsb[cur + rr * 64 + sR * 16];
      const float4 ahi = *(const float4*)&ldsb[cur + 8192 + rr * 64 + sR * 16];
      const float4 wlo = *(const float4*)&ws0l[kt * 32 + c4 * 8];
      const float4 whi = *(const float4*)&ws0l[kt * 32 + c4 * 8 + 4];
      rdp += alo.x * wlo.x + alo.y * wlo.y + alo.z * wlo.z + alo.w * wlo.w +
             ahi.x * whi.x + ahi.y * whi.y + ahi.z * whi.z + ahi.w * whi.w;
    }
    const half8 w2f = *(const half8*)&wlds[kt * 32 + g * 8];
    bq[0] *= w2f;
    bq[1] *= w2f;  // B' = Ws2 (.) q
#pragma unroll
    for (int i = 0; i < 4; ++i)
#pragma unroll
      for (int j = 0; j < 2; ++j)
        accS[i][j] = __builtin_amdgcn_mfma_f32_16x16x32_f16(af[i], bp[j], accS[i][j], 0, 0, 0);
#pragma unroll
    for (int i = 0; i < 4; ++i)
#pragma unroll
      for (int j = 0; j < 2; ++j)
        accH[i][j] = __builtin_amdgcn_mfma_f32_16x16x32_f16(af[i], bq[j], accH[i][j], 0, 0, 0);
    __syncthreads();
  }

  // rdvec: combine the 4 per-row partials (adjacent lanes) and store.
  if (doRd) {
    float rv = rdp;
    rv += __shfl_xor(rv, 1);
    rv += __shfl_xor(rv, 2);
    if (c4 == 0) rdvec[(long)b * RD + m0 + rr] = rv;
  }

  // C/D layout: col = lane&15, row = g*4 + reg.
  const int cr = g * 4, cc = fr;
  float cv[2], hv[2];
#pragma unroll
  for (int j = 0; j < 2; ++j) {
    const long col = (long)b * TD + n0 + 32 * wc + 16 * j + cc;
    cv[j] = cvec[col];
    hv[j] = h1[col];
  }

  // Per-wave stats (32 cols), staged into reused LDS: [wr][wc][64 rows].
  float* smx = (float*)(void*)ldsb;  // 512 floats
  float* slv = smx + 512;
  float* shv = slv + 512;
#pragma unroll
  for (int i = 0; i < 4; ++i) {
#pragma unroll
    for (int r = 0; r < 4; ++r) {
      float mx = fmaxf(accS[i][0][r] + cv[0], accS[i][1][r] + cv[1]);
      mx = fmaxf(mx, __shfl_xor(mx, 1));
      mx = fmaxf(mx, __shfl_xor(mx, 2));
      mx = fmaxf(mx, __shfl_xor(mx, 4));
      mx = fmaxf(mx, __shfl_xor(mx, 8));
      float l = 0.f, hs = 0.f;
#pragma unroll
      for (int j = 0; j < 2; ++j) {
        const float e = __expf(accS[i][j][r] + cv[j] - mx);
        l += e;
        hs += e * (accH[i][j][r] + hv[j]);
      }
      l += __shfl_xor(l, 1); hs += __shfl_xor(hs, 1);
      l += __shfl_xor(l, 2); hs += __shfl_xor(hs, 2);
      l += __shfl_xor(l, 4); hs += __shfl_xor(hs, 4);
      l += __shfl_xor(l, 8); hs += __shfl_xor(hs, 8);
      if (cc == 0) {
        const int rw = 16 * i + cr + r;  // 0..63 within the wr half
        smx[wr * 256 + wc * 64 + rw] = mx;
        slv[wr * 256 + wc * 64 + rw] = l;
        shv[wr * 256 + wc * 64 + rw] = hs;
      }
    }
  }
  __syncthreads();
  // Cross-wc combine: 128 threads, one row each; emit chunk nt.
  if (tid < 128) {
    const int rw = tid & 63, w2 = tid >> 6;
    float m4[4], gm = -1e30f;
#pragma unroll
    for (int c = 0; c < 4; ++c) {
      m4[c] = smx[w2 * 256 + c * 64 + rw];
      gm = fmaxf(gm, m4[c]);
    }
    float L = 0.f, H = 0.f;
#pragma unroll
    for (int c = 0; c < 4; ++c) {
      const float sc = __expf(m4[c] - gm);
      L += slv[w2 * 256 + c * 64 + rw] * sc;
      H += shv[w2 * 256 + c * 64 + rw] * sc;
    }
    const long gidx = (long)b * RD + m0 + 64 * w2 + rw;
    Ms[(long)nt * BR + gidx] = gm;
    Ls[(long)nt * BR + gidx] = L;
    Hs[(long)nt * BR + gidx] = H;
  }
}

// ---------------- K4: combine 4 chunk-stats per row.
__global__ __launch_bounds__(256) void combine(
    const float* __restrict__ Ms, const float* __restrict__ Ls,
    const float* __restrict__ Hs, const float* __restrict__ rdvec,
    const float* __restrict__ bs, float* __restrict__ out) {
  const int row = blockIdx.x * 256 + threadIdx.x;
  float mv[4];
  float gm = -1e30f;
#pragma unroll
  for (int c = 0; c < 4; ++c) {
    mv[c] = Ms[(long)c * BR + row];
    gm = fmaxf(gm, mv[c]);
  }
  float L = 0.f, HS = 0.f;
#pragma unroll
  for (int c = 0; c < 4; ++c) {
    const float sc = __expf(mv[c] - gm);
    L += Ls[(long)c * BR + row] * sc;
    HS += Hs[(long)c * BR + row] * sc;
  }
  out[row] = HS / L + rdvec[row] + bs[0];
}

extern "C" void kernel_launch(void* const* d_in, const int* in_sizes, int n_in,
                              void* d_out, int out_size, void* d_ws, size_t ws_size,
                              hipStream_t stream) {
  const float* region = (const float*)d_in[0];
  const float* query  = (const float*)d_in[1];
  const float* Wr     = (const float*)d_in[2];
  const float* br     = (const float*)d_in[3];
  const float* Wq     = (const float*)d_in[4];
  // d_in[5] = bq: t-constant per score row, cancels in softmax.
  const float* Ws     = (const float*)d_in[6];
  const float* bs     = (const float*)d_in[7];
  float* out = (float*)d_out;

  // ws layout (region16 slot retired; offsets kept for safety).
  char* p = (char*)d_ws;
  _Float16* query16  = (_Float16*)(p + (32u << 20));   // 16 MiB
  _Float16* Qp       = (_Float16*)(p + (48u << 20));   // 16 MiB
  _Float16* M2       = (_Float16*)(p + (64u << 20));   // 2 MiB
  _Float16* Ws16     = (_Float16*)(p + (66u << 20));   // 4 KiB (Ws1|Ws2)
  float*    wqbr     = (float*)(p + (66u << 20) + 8192);    // 4 KiB
  _Float16* wqbr16   = (_Float16*)(p + (66u << 20) + 12288);// 2 KiB
  float*    cvec     = (float*)(p + (66u << 20) + 16384);   // 32 KiB
  float*    rdvec    = (float*)(p + (66u << 20) + 65536);   // 64 KiB
  float*    h1       = (float*)(p + (66u << 20) + 131072);  // 32 KiB
  float*    Ms       = (float*)(p + (67u << 20));      // 3 x 256 KiB stats
  float*    Ls       = Ms + 4 * BR;
  float*    Hs       = Ls + 4 * BR;

  // K1: M2 GEMM + Ws16 + wqbr + query16/h1 (no region traffic).
  prep_all<<<dim3(514 + BD * TD / 4), 256, 0, stream>>>(
      Wr, Wq, Ws, br, query, M2, Ws16, wqbr, wqbr16, query16, h1);
  // K2: Qp = NT(query16, M2) + cvec epilogue (counted-vmcnt 4-slot).
  qp_gemm<<<dim3(512), 512, 0, stream>>>(query16, M2, Qp, wqbr16, cvec);
  // K3: fused S/H + stats, A = region fp32 direct; nt==0 blocks emit rdvec.
  gemm_fused<<<dim3(512), 512, 0, stream>>>(
      region, Qp, query16, Ms, Ls, Hs, cvec, h1, Ws16, Ws, rdvec,
      (long)RD * DD, (long)TD * DD);
  // K4: out = HS/L + region.Ws0 + bs over 4 chunks.
  combine<<<dim3(BR / 256), 256, 0, stream>>>(Ms, Ls, Hs, rdvec, bs, out);
}

// Round 10
// 265.214 us; speedup vs baseline: 1.4512x; 1.4512x over previous
//
#include <hip/hip_runtime.h>

// CrossModalAttentionScorer — round 18: fix r17's register spill.
// B=16, R=1024, T=512, D=H=1024.
//
// r17 post-mortem: WRITE_SIZE 768KB -> 291MB = scratch spill. Cause:
// __launch_bounds__(512,4) caps VGPR at 64; the fp32-A path (float4 lo/hi
// pairs + cvt8 temps) no longer fits (r13's fp16 path fit exactly). Fix:
// (512,2) -> 128 VGPR budget. Occupancy unchanged: 70KB LDS already limits
// to 2 blocks/CU and grid=512 is exactly 2/CU.
//
//   K1 prep_all: M2 = NT(Wr,Wq); Ws16; wqbr(+16); query16 + h1. (2562 blks)
//   K2 qp:       Qp = NT(query16, M2), r13's counted-vmcnt 4-slot (best).
//   K3 fused:    accS = NT(region_f32, Qp)+cvec, accH = NT(region, Ws2.q),
//                h1 in epilogue; A staged fp32, cvt8 after ds_read; nt==0
//                blocks emit rdvec. launch_bounds (512,2).
//   K4 combine:  4 chunk-stats per row (r13).
//
// Hard-won constraints (measured):
//   - counted-vmcnt on K3's 128^2 tile: null-to-negative (r10/r11).
//   - per-block __threadfence fan-in: +100us fence storm (r12). Never.
//   - conv/GEMM same-launch overlap: additive, no hiding (r14).
//   - K2 BK=64: null-to-slightly-negative (r15). Reverted.
//   - fixed overhead ~95-100us, launch-count-independent (r12/r13).
//   - LDS staging permutation NEVER cancels on read: reader must XOR (r16).
//   - launch_bounds waves/EU arg caps VGPR: (512,4)=64 regs -> fp32 path
//     spills 291MB scratch (r17). Check VGPR fit when widening data paths.

#define BD 16
#define RD 1024
#define TD 512
#define DD 1024
#define BR (BD * RD)

typedef _Float16 half8 __attribute__((ext_vector_type(8)));
typedef _Float16 half4 __attribute__((ext_vector_type(4)));
typedef float floatx4 __attribute__((ext_vector_type(4)));

__device__ __forceinline__ float wave_sum(float v) {
#pragma unroll
  for (int off = 32; off > 0; off >>= 1) v += __shfl_down(v, off);
  return v;
}

__device__ __forceinline__ half8 cvt8(float4 a, float4 b) {
  half8 h = {(_Float16)a.x, (_Float16)a.y, (_Float16)a.z, (_Float16)a.w,
             (_Float16)b.x, (_Float16)b.y, (_Float16)b.z, (_Float16)b.w};
  return h;
}

// Async global->LDS, 16 B/lane. LDS dest is wave-uniform base + lane*16.
__device__ __forceinline__ void gl16(const _Float16* g, _Float16* l) {
  __builtin_amdgcn_global_load_lds(
      (const __attribute__((address_space(1))) void*)g,
      (__attribute__((address_space(3))) void*)l, 16, 0, 0);
}
__device__ __forceinline__ void gl16b(const void* g, void* l) {
  __builtin_amdgcn_global_load_lds(
      (const __attribute__((address_space(1))) void*)g,
      (__attribute__((address_space(3))) void*)l, 16, 0, 0);
}

#define VMW_(N) asm volatile("s_waitcnt vmcnt(" #N ")" ::: "memory")
#define VMW(N) VMW_(N)
#define BARR                        \
  __builtin_amdgcn_s_barrier();     \
  asm volatile("" ::: "memory")

// ---------------- K1: only what K2 (and K3's small vectors) need.
// blk [0,256):      M2 = NT(Wr,Wq) 64x64 tile
// blk [256,258):    Ws1|Ws2 -> fp16
// blk [258,514):    wqbr = Wq @ br
// blk [514,2562):   query -> fp16, h1 = query.Ws1 (4 rows/block)
__global__ __launch_bounds__(256) void prep_all(
    const float* __restrict__ Wr, const float* __restrict__ Wq,
    const float* __restrict__ Ws, const float* __restrict__ br,
    const float* __restrict__ query,
    _Float16* __restrict__ M2, _Float16* __restrict__ Ws16,
    float* __restrict__ wqbr, _Float16* __restrict__ wqbr16,
    _Float16* __restrict__ q16, float* __restrict__ h1) {
  __shared__ __align__(16) _Float16 lds[2 * 2 * 2048];  // 16 KB (M2 path)
  const int blk = blockIdx.x, tid = threadIdx.x;

  if (blk < 256) {  // ---- M2 = NT(Wr, Wq), 64x64 tile, K=1024
    const int m0 = (blk >> 4) * 64, n0 = (blk & 15) * 64;
    const int lane = tid & 63, w = tid >> 6;
    const int wr = w >> 1, wc = w & 1;
    const int srow = tid >> 2, slot = tid & 3;
    const int scol = (slot ^ ((srow >> 1) & 3)) * 8;
    const long offA = (long)(m0 + srow) * DD + scol;
    const long offB = (long)(n0 + srow) * DD + scol;
    const int wofs = srow * 32 + slot * 8;
    const int NK = DD / 32;
    float4 a0, a1, b0, b1;
    a0 = *(const float4*)(Wr + offA); a1 = *(const float4*)(Wr + offA + 4);
    b0 = *(const float4*)(Wq + offB); b1 = *(const float4*)(Wq + offB + 4);
    *(int4*)&lds[wofs] = *(int4*)&(const half8&)cvt8(a0, a1);
    {
      half8 hb = cvt8(b0, b1);
      *(half8*)&lds[2048 + wofs] = hb;
    }
    a0 = *(const float4*)(Wr + offA + 32); a1 = *(const float4*)(Wr + offA + 36);
    b0 = *(const float4*)(Wq + offB + 32); b1 = *(const float4*)(Wq + offB + 36);
    __syncthreads();
    floatx4 acc[2][2] = {};
    const int fr = lane & 15, g = lane >> 4;
    const int fs = (g ^ ((fr >> 1) & 3)) * 8;
    for (int kt = 0; kt < NK; ++kt) {
      const int cur = (kt & 1) * 4096, nxt = ((kt + 1) & 1) * 4096;
      if (kt + 1 < NK) {
        half8 ha = cvt8(a0, a1), hb = cvt8(b0, b1);
        *(half8*)&lds[nxt + wofs] = ha;
        *(half8*)&lds[nxt + 2048 + wofs] = hb;
      }
      if (kt + 2 < NK) {
        const long go = (long)(kt + 2) * 32;
        a0 = *(const float4*)(Wr + offA + go); a1 = *(const float4*)(Wr + offA + go + 4);
        b0 = *(const float4*)(Wq + offB + go); b1 = *(const float4*)(Wq + offB + go + 4);
      }
      half8 af[2], bf[2];
#pragma unroll
      for (int i = 0; i < 2; ++i)
        af[i] = *(const half8*)&lds[cur + (32 * wr + 16 * i + fr) * 32 + fs];
#pragma unroll
      for (int j = 0; j < 2; ++j)
        bf[j] = *(const half8*)&lds[cur + 2048 + (32 * wc + 16 * j + fr) * 32 + fs];
#pragma unroll
      for (int i = 0; i < 2; ++i)
#pragma unroll
        for (int j = 0; j < 2; ++j)
          acc[i][j] = __builtin_amdgcn_mfma_f32_16x16x32_f16(af[i], bf[j], acc[i][j], 0, 0, 0);
      __syncthreads();
    }
    const int cr = g * 4, cc = fr;
#pragma unroll
    for (int i = 0; i < 2; ++i)
#pragma unroll
      for (int r = 0; r < 4; ++r)
#pragma unroll
        for (int j = 0; j < 2; ++j)
          M2[(long)(m0 + 32 * wr + 16 * i + cr + r) * DD + n0 + 32 * wc + 16 * j + cc] =
              (_Float16)acc[i][j][r];
  } else if (blk < 258) {  // ---- Ws1|Ws2
    const long i = (long)(blk - 256) * 1024 + tid * 4;
    const float4 v = *(const float4*)&Ws[DD + i];
    half4 h = {(_Float16)v.x, (_Float16)v.y, (_Float16)v.z, (_Float16)v.w};
    *(half4*)&Ws16[i] = h;
  } else if (blk < 514) {  // ---- wqbr = Wq @ br
    const int row = (blk - 258) * 4 + (tid >> 6);
    const int lane = tid & 63;
    const float* x = Wq + (long)row * DD;
    float s = 0.f;
    for (int k = lane; k < DD; k += 64) s += x[k] * br[k];
    s = wave_sum(s);
    if (lane == 0) {
      wqbr[row] = s;
      wqbr16[row] = (_Float16)s;
    }
  } else {  // ---- query conv + h1 = q.Ws1, wave-per-row
    const int wid = tid >> 6, lane = tid & 63;
    const long row = (long)(blk - 514) * 4 + wid;
    const float* src = query + row * DD;
    _Float16* dst = q16 + row * DD;
    float hq = 0.f;
#pragma unroll
    for (int it = 0; it < 4; ++it) {
      const int c = it * 256 + lane * 4;
      const float4 v = *(const float4*)&src[c];
      const float4 w1 = *(const float4*)&Ws[DD + c];
      half4 h = {(_Float16)v.x, (_Float16)v.y, (_Float16)v.z, (_Float16)v.w};
      *(half4*)&dst[c] = h;
      hq += v.x * w1.x + v.y * w1.y + v.z * w1.z + v.w * w1.w;
    }
    hq = wave_sum(hq);
    if (lane == 0) h1[row] = hq;
  }
}

// ---------------- K2: Qp = NT(query16, M2) — r13 counted-vmcnt 4-slot.
#define STAGE2(hh, sl)                                  \
  {                                                     \
    const long go_ = (long)(hh) * 32;                   \
    gl16(gA + go_, &lds[(sl) * 8192 + wbase]);          \
    gl16(gB + go_, &lds[(sl) * 8192 + 4096 + wbase]);   \
  }

#define COMP2(h, sl)                                                           \
  {                                                                            \
    half8 af[2], bf[4];                                                        \
    _Pragma("unroll") for (int i = 0; i < 2; ++i)                              \
      af[i] = *(const half8*)&lds[(sl) * 8192 + (32 * wr + 16 * i + fr) * 32 + fs]; \
    _Pragma("unroll") for (int j = 0; j < 4; ++j)                              \
      bf[j] = *(const half8*)&lds[(sl) * 8192 + 4096 + (64 * wc + 16 * j + fr) * 32 + fs]; \
    if (wc == 0) {                                                             \
      const half8 wb = *(const half8*)&wq_lds[(h) * 32 + g * 8];               \
      _Pragma("unroll") for (int i = 0; i < 2; ++i)                            \
        _Pragma("unroll") for (int e = 0; e < 8; ++e)                          \
          cvp[i] += (float)af[i][e] * (float)wb[e];                            \
    }                                                                          \
    __builtin_amdgcn_s_setprio(1);                                             \
    _Pragma("unroll") for (int i = 0; i < 2; ++i)                              \
      _Pragma("unroll") for (int j = 0; j < 4; ++j)                            \
        acc[i][j] = __builtin_amdgcn_mfma_f32_16x16x32_f16(af[i], bf[j], acc[i][j], 0, 0, 0); \
    __builtin_amdgcn_s_setprio(0);                                             \
  }

__global__ __launch_bounds__(512, 4) void qp_gemm(
    const _Float16* __restrict__ A, const _Float16* __restrict__ B,
    _Float16* __restrict__ C, const _Float16* __restrict__ wq16,
    float* __restrict__ cvec) {
  __shared__ __align__(16) _Float16 lds[4 * 8192];   // 64 KB: 4 slots
  __shared__ __align__(16) _Float16 wq_lds[1024];
  const int lin = blockIdx.x;
  const int s = lin & 7, u = lin >> 3;  // XCD s owns m-strip [8s, 8s+8)
  const int mt = s * 8 + (u >> 3), nt = u & 7;
  const int m0 = mt * 128, n0 = nt * 128;
  const int tid = threadIdx.x, lane = tid & 63, w = tid >> 6;
  const int wr = w >> 1, wc = w & 1;

  const int lrow = lane >> 2, slot = lane & 3;
  const int scol = (slot ^ ((lrow >> 1) & 3)) * 8;
  const int srow = 16 * w + lrow;  // 0..127
  const _Float16* gA = A + (long)(m0 + srow) * DD + scol;
  const _Float16* gB = B + (long)(n0 + srow) * DD + scol;
  const int wbase = 512 * w;  // halfs: lane l lands at wbase + 8*l

  if (tid < 128) *(int4*)&wq_lds[tid * 8] = *(const int4*)&wq16[tid * 8];
  __syncthreads();  // wq_lds visible; clean vmcnt slate

  floatx4 acc[2][4] = {};
  float cvp[2] = {0.f, 0.f};
  const int fr = lane & 15, g = lane >> 4;
  const int fs = (g ^ ((fr >> 1) & 3)) * 8;

  STAGE2(0, 0); STAGE2(1, 1); STAGE2(2, 2);  // 6 outstanding
  VMW(4); BARR;                              // slot 0 landed everywhere

  for (int hb = 0; hb < 28; hb += 4) {
    STAGE2(hb + 3, 3); COMP2(hb + 0, 0); VMW(4); BARR;
    STAGE2(hb + 4, 0); COMP2(hb + 1, 1); VMW(4); BARR;
    STAGE2(hb + 5, 1); COMP2(hb + 2, 2); VMW(4); BARR;
    STAGE2(hb + 6, 2); COMP2(hb + 3, 3); VMW(4); BARR;
  }
  STAGE2(31, 3); COMP2(28, 0); VMW(4); BARR;
  COMP2(29, 1); VMW(2); BARR;
  COMP2(30, 2); VMW(0); BARR;
  COMP2(31, 3);

  if (wc == 0 && nt == 0) {
#pragma unroll
    for (int i = 0; i < 2; ++i) {
      float c = cvp[i];
      c += __shfl_xor(c, 16);
      c += __shfl_xor(c, 32);
      if (lane < 16) cvec[m0 + 32 * wr + 16 * i + lane] = c;
    }
  }

  const int cr = g * 4, cc = fr;
#pragma unroll
  for (int i = 0; i < 2; ++i)
#pragma unroll
    for (int r = 0; r < 4; ++r)
#pragma unroll
      for (int j = 0; j < 4; ++j)
        C[(long)(m0 + 32 * wr + 16 * i + cr + r) * DD + n0 + 64 * wc + 16 * j + cc] =
            (_Float16)acc[i][j][r];
}

// ---------------- K3: fused S/H GEMM + split-softmax stats, A = fp32 direct.
// 8 waves 2(m) x 4(n); wave 64x32. LDS slot (32 KB): A32-c0 [0,8K),
// A32-c1 [8K,16K), P [16K,24K), Q [24K,32K). 2 slots = 64 KB. nt==0 blocks
// also accumulate rdvec = region.Ws0. launch_bounds (512,2): 128-VGPR
// budget — the fp32 path spills at 64 (r17: 291MB scratch writes).
__global__ __launch_bounds__(512, 2) void gemm_fused(
    const float* __restrict__ Af, const _Float16* __restrict__ B0,
    const _Float16* __restrict__ B1,
    float* __restrict__ Ms, float* __restrict__ Ls, float* __restrict__ Hs,
    const float* __restrict__ cvec, const float* __restrict__ h1,
    const _Float16* __restrict__ wsh, const float* __restrict__ ws0,
    float* __restrict__ rdvec, long sA, long sB) {
  __shared__ __align__(16) char ldsb[2 * 32768];  // 64 KB
  __shared__ __align__(16) _Float16 wlds[1024];   // Ws2 fp16
  __shared__ __align__(16) float ws0l[1024];      // Ws0 fp32

  const int lin = blockIdx.x;
  const int s = lin & 7, u = lin >> 3;  // XCD s owns batches 2s, 2s+1
  const int b = 2 * s + (u >> 5);
  const int t = u & 31;
  const int mt = t >> 2, nt = t & 3;
  const int m0 = mt * 128, n0 = nt * 128;
  const float* Ab = Af + (long)b * sA;
  B0 += (long)b * sB;
  B1 += (long)b * sB;

  const int tid = threadIdx.x, lane = tid & 63, w = tid >> 6;
  const int wr = w >> 2, wc = w & 3;  // 2 x 4

  const int lrow = lane >> 2, slot = lane & 3;
  const int scol = (slot ^ ((lrow >> 1) & 3)) * 8;
  const int srow = 16 * w + lrow;  // 0..127
  const float*    gA = Ab + (long)(m0 + srow) * DD + scol;
  const _Float16* gP = B0 + (long)(n0 + srow) * DD + scol;
  const _Float16* gQ = B1 + (long)(n0 + srow) * DD + scol;
  const int wB = 1024 * w;

  if (tid < 128) *(int4*)&wlds[tid * 8] = *(const int4*)&wsh[1024 + tid * 8];
  if (tid >= 256) *(float4*)&ws0l[(tid - 256) * 4] = *(const float4*)&ws0[(tid - 256) * 4];

  gl16b(gA,     ldsb + wB);
  gl16b(gA + 4, ldsb + 8192 + wB);
  gl16b(gP,     ldsb + 16384 + wB);
  gl16b(gQ,     ldsb + 24576 + wB);
  __syncthreads();

  floatx4 accS[4][2] = {};
  floatx4 accH[4][2] = {};
  float rdp = 0.f;
  const int fr = lane & 15, g = lane >> 4;
  const int fs2 = (g ^ ((fr >> 1) & 3)) * 16;  // byte slot offset (READ XOR)
  const bool doRd = (nt == 0);
  const int rr = tid >> 2, c4 = tid & 3;       // rdvec: 4 threads per row
  const int sR = c4 ^ ((rr >> 1) & 3);
  const int NK = DD / 32;

  for (int kt = 0; kt < NK; ++kt) {
    const int cur = (kt & 1) * 32768;
    const int nxt = cur ^ 32768;
    if (kt + 1 < NK) {
      const long go = (long)(kt + 1) * 32;
      gl16b(gA + go,     ldsb + nxt + wB);
      gl16b(gA + go + 4, ldsb + nxt + 8192 + wB);
      gl16b(gP + go,     ldsb + nxt + 16384 + wB);
      gl16b(gQ + go,     ldsb + nxt + 24576 + wB);
    }
    half8 af[4], bp[2], bq[2];
#pragma unroll
    for (int i = 0; i < 4; ++i) {
      const int rA = 64 * wr + 16 * i + fr;
      const float4 lo = *(const float4*)&ldsb[cur + rA * 64 + fs2];
      const float4 hi = *(const float4*)&ldsb[cur + 8192 + rA * 64 + fs2];
      af[i] = cvt8(lo, hi);  // identical rounding to the old K1 conversion
    }
#pragma unroll
    for (int j = 0; j < 2; ++j)
      bp[j] = *(const half8*)&ldsb[cur + 16384 + (32 * wc + 16 * j + fr) * 64 + fs2];
#pragma unroll
    for (int j = 0; j < 2; ++j)
      bq[j] = *(const half8*)&ldsb[cur + 24576 + (32 * wc + 16 * j + fr) * 64 + fs2];
    if (doRd) {  // rdvec partial: row rr, float-cols kt*32 + 8*c4 .. +8
      const float4 alo = *(const float4*)&ldsb[cur + rr * 64 + sR * 16];
      const float4 ahi = *(const float4*)&ldsb[cur + 8192 + rr * 64 + sR * 16];
      const float4 wlo = *(const float4*)&ws0l[kt * 32 + c4 * 8];
      const float4 whi = *(const float4*)&ws0l[kt * 32 + c4 * 8 + 4];
      rdp += alo.x * wlo.x + alo.y * wlo.y + alo.z * wlo.z + alo.w * wlo.w +
             ahi.x * whi.x + ahi.y * whi.y + ahi.z * whi.z + ahi.w * whi.w;
    }
    const half8 w2f = *(const half8*)&wlds[kt * 32 + g * 8];
    bq[0] *= w2f;
    bq[1] *= w2f;  // B' = Ws2 (.) q
#pragma unroll
    for (int i = 0; i < 4; ++i)
#pragma unroll
      for (int j = 0; j < 2; ++j)
        accS[i][j] = __builtin_amdgcn_mfma_f32_16x16x32_f16(af[i], bp[j], accS[i][j], 0, 0, 0);
#pragma unroll
    for (int i = 0; i < 4; ++i)
#pragma unroll
      for (int j = 0; j < 2; ++j)
        accH[i][j] = __builtin_amdgcn_mfma_f32_16x16x32_f16(af[i], bq[j], accH[i][j], 0, 0, 0);
    __syncthreads();
  }

  // rdvec: combine the 4 per-row partials (adjacent lanes) and store.
  if (doRd) {
    float rv = rdp;
    rv += __shfl_xor(rv, 1);
    rv += __shfl_xor(rv, 2);
    if (c4 == 0) rdvec[(long)b * RD + m0 + rr] = rv;
  }

  // C/D layout: col = lane&15, row = g*4 + reg.
  const int cr = g * 4, cc = fr;
  float cv[2], hv[2];
#pragma unroll
  for (int j = 0; j < 2; ++j) {
    const long col = (long)b * TD + n0 + 32 * wc + 16 * j + cc;
    cv[j] = cvec[col];
    hv[j] = h1[col];
  }

  // Per-wave stats (32 cols), staged into reused LDS: [wr][wc][64 rows].
  float* smx = (float*)(void*)ldsb;  // 512 floats
  float* slv = smx + 512;
  float* shv = slv + 512;
#pragma unroll
  for (int i = 0; i < 4; ++i) {
#pragma unroll
    for (int r = 0; r < 4; ++r) {
      float mx = fmaxf(accS[i][0][r] + cv[0], accS[i][1][r] + cv[1]);
      mx = fmaxf(mx, __shfl_xor(mx, 1));
      mx = fmaxf(mx, __shfl_xor(mx, 2));
      mx = fmaxf(mx, __shfl_xor(mx, 4));
      mx = fmaxf(mx, __shfl_xor(mx, 8));
      float l = 0.f, hs = 0.f;
#pragma unroll
      for (int j = 0; j < 2; ++j) {
        const float e = __expf(accS[i][j][r] + cv[j] - mx);
        l += e;
        hs += e * (accH[i][j][r] + hv[j]);
      }
      l += __shfl_xor(l, 1); hs += __shfl_xor(hs, 1);
      l += __shfl_xor(l, 2); hs += __shfl_xor(hs, 2);
      l += __shfl_xor(l, 4); hs += __shfl_xor(hs, 4);
      l += __shfl_xor(l, 8); hs += __shfl_xor(hs, 8);
      if (cc == 0) {
        const int rw = 16 * i + cr + r;  // 0..63 within the wr half
        smx[wr * 256 + wc * 64 + rw] = mx;
        slv[wr * 256 + wc * 64 + rw] = l;
        shv[wr * 256 + wc * 64 + rw] = hs;
      }
    }
  }
  __syncthreads();
  // Cross-wc combine: 128 threads, one row each; emit chunk nt.
  if (tid < 128) {
    const int rw = tid & 63, w2 = tid >> 6;
    float m4[4], gm = -1e30f;
#pragma unroll
    for (int c = 0; c < 4; ++c) {
      m4[c] = smx[w2 * 256 + c * 64 + rw];
      gm = fmaxf(gm, m4[c]);
    }
    float L = 0.f, H = 0.f;
#pragma unroll
    for (int c = 0; c < 4; ++c) {
      const float sc = __expf(m4[c] - gm);
      L += slv[w2 * 256 + c * 64 + rw] * sc;
      H += shv[w2 * 256 + c * 64 + rw] * sc;
    }
    const long gidx = (long)b * RD + m0 + 64 * w2 + rw;
    Ms[(long)nt * BR + gidx] = gm;
    Ls[(long)nt * BR + gidx] = L;
    Hs[(long)nt * BR + gidx] = H;
  }
}

// ---------------- K4: combine 4 chunk-stats per row.
__global__ __launch_bounds__(256) void combine(
    const float* __restrict__ Ms, const float* __restrict__ Ls,
    const float* __restrict__ Hs, const float* __restrict__ rdvec,
    const float* __restrict__ bs, float* __restrict__ out) {
  const int row = blockIdx.x * 256 + threadIdx.x;
  float mv[4];
  float gm = -1e30f;
#pragma unroll
  for (int c = 0; c < 4; ++c) {
    mv[c] = Ms[(long)c * BR + row];
    gm = fmaxf(gm, mv[c]);
  }
  float L = 0.f, HS = 0.f;
#pragma unroll
  for (int c = 0; c < 4; ++c) {
    const float sc = __expf(mv[c] - gm);
    L += Ls[(long)c * BR + row] * sc;
    HS += Hs[(long)c * BR + row] * sc;
  }
  out[row] = HS / L + rdvec[row] + bs[0];
}

extern "C" void kernel_launch(void* const* d_in, const int* in_sizes, int n_in,
                              void* d_out, int out_size, void* d_ws, size_t ws_size,
                              hipStream_t stream) {
  const float* region = (const float*)d_in[0];
  const float* query  = (const float*)d_in[1];
  const float* Wr     = (const float*)d_in[2];
  const float* br     = (const float*)d_in[3];
  const float* Wq     = (const float*)d_in[4];
  // d_in[5] = bq: t-constant per score row, cancels in softmax.
  const float* Ws     = (const float*)d_in[6];
  const float* bs     = (const float*)d_in[7];
  float* out = (float*)d_out;

  // ws layout (region16 slot retired; offsets kept for safety).
  char* p = (char*)d_ws;
  _Float16* query16  = (_Float16*)(p + (32u << 20));   // 16 MiB
  _Float16* Qp       = (_Float16*)(p + (48u << 20));   // 16 MiB
  _Float16* M2       = (_Float16*)(p + (64u << 20));   // 2 MiB
  _Float16* Ws16     = (_Float16*)(p + (66u << 20));   // 4 KiB (Ws1|Ws2)
  float*    wqbr     = (float*)(p + (66u << 20) + 8192);    // 4 KiB
  _Float16* wqbr16   = (_Float16*)(p + (66u << 20) + 12288);// 2 KiB
  float*    cvec     = (float*)(p + (66u << 20) + 16384);   // 32 KiB
  float*    rdvec    = (float*)(p + (66u << 20) + 65536);   // 64 KiB
  float*    h1       = (float*)(p + (66u << 20) + 131072);  // 32 KiB
  float*    Ms       = (float*)(p + (67u << 20));      // 3 x 256 KiB stats
  float*    Ls       = Ms + 4 * BR;
  float*    Hs       = Ls + 4 * BR;

  // K1: M2 GEMM + Ws16 + wqbr + query16/h1 (no region traffic).
  prep_all<<<dim3(514 + BD * TD / 4), 256, 0, stream>>>(
      Wr, Wq, Ws, br, query, M2, Ws16, wqbr, wqbr16, query16, h1);
  // K2: Qp = NT(query16, M2) + cvec epilogue (counted-vmcnt 4-slot).
  qp_gemm<<<dim3(512), 512, 0, stream>>>(query16, M2, Qp, wqbr16, cvec);
  // K3: fused S/H + stats, A = region fp32 direct; nt==0 blocks emit rdvec.
  gemm_fused<<<dim3(512), 512, 0, stream>>>(
      region, Qp, query16, Ms, Ls, Hs, cvec, h1, Ws16, Ws, rdvec,
      (long)RD * DD, (long)TD * DD);
  // K4: out = HS/L + region.Ws0 + bs over 4 chunks.
  combine<<<dim3(BR / 256), 256, 0, stream>>>(Ms, Ls, Hs, rdvec, bs, out);
}